// Round 3
// baseline (534.092 us; speedup 1.0000x reference)
//
#include <hip/hip_runtime.h>

#define NROWS  32768
#define DIM    64
#define KCODES 1024
#define NELEM  (NROWS * DIM)      // 2097152
#define CHUNKS 4
#define CPC    256                // codes per chunk
#define RPB    128                // rows per block (256 threads, 2 per row)
#define NBLK_B 256                // vq_out blocks

typedef float v2f __attribute__((ext_vector_type(2)));

// numpy pairwise sum-of-squares over 16 float4 (64 elems), streaming form:
// accumulator r[k] sums v[8i+k] sequentially over i (numpy's 8-way unrolled
// block), final combine ((r0+r1)+(r2+r3))+((r4+r5)+(r6+r7)). contract(off) so
// the square can't fuse into the add (numpy squares first, then sums).
// Bit-identical to rounds 1-2's verified np_sumsq64 (absmax 0.0).
// Live set: 2 float4 + 8 accs — no register-pressure cliff.
__device__ __forceinline__ float np_sumsq_f4(const float4* __restrict__ p) {
#pragma clang fp contract(off)
  float4 a = p[0], b = p[1];
  float r0 = a.x * a.x, r1 = a.y * a.y, r2 = a.z * a.z, r3 = a.w * a.w;
  float r4 = b.x * b.x, r5 = b.y * b.y, r6 = b.z * b.z, r7 = b.w * b.w;
#pragma unroll
  for (int i = 1; i < 8; ++i) {
    a = p[2 * i]; b = p[2 * i + 1];
    r0 += a.x * a.x; r1 += a.y * a.y; r2 += a.z * a.z; r3 += a.w * a.w;
    r4 += b.x * b.x; r5 += b.y * b.y; r6 += b.z * b.z; r7 += b.w * b.w;
  }
  return ((r0 + r1) + (r2 + r3)) + ((r4 + r5) + (r6 + r7));
}

// Kernel A: fused se-prep + distances + per-chunk argmin.
// Grid 1024 = 256 row-groups x 4 K-chunks -> 4 blocks/CU, 4 waves/SIMD.
// Thread pair (2t,2t+1) owns one row; each thread keeps HALF the row (16 v2f
// = 32 VGPRs) resident — small enough that the allocator can't deny it
// (rounds 1-2: full 64-float row was silently demoted to in-loop reloads).
// Per code: 16 chained pk_fma on the half-dot, shfl_xor(1) combine, then
// d = fmaf(-2, dot, fl(sx+se[c])) — bit-exact vs the ref's
// fl(fl(sx+se) - fl(2*dot)) since fl(2*dot) is exact.
// Strict-< ascending scan keeps the lowest index on ties within the chunk;
// cross-chunk ties resolved by u64 key min in kernel B.
__global__ __launch_bounds__(256, 4) void vq_dist(const float* __restrict__ x,
                                                  const float* __restrict__ w,
                                                  unsigned long long* __restrict__ keys4,
                                                  double* __restrict__ loss,
                                                  unsigned int* __restrict__ cnt) {
  __shared__ float se[CPC];
  const int t = threadIdx.x;
  const int g = blockIdx.x >> 2;
  const int chunk = blockIdx.x & 3;
  const int c0 = chunk * CPC;

  if (blockIdx.x == 0 && t == 0) { *loss = 0.0; *cnt = 0u; }

  // se for this chunk's 256 codes: one per thread, numpy pairwise rounding.
  se[t] = np_sumsq_f4((const float4*)(w + (size_t)(c0 + t) * DIM));

  // This thread's row / half.
  const int row = g * RPB + (t >> 1);
  const int half = t & 1;
  const float4* xr = (const float4*)(x + (size_t)row * DIM);

  // sx: stream the FULL row in numpy order (both pair-threads redundantly).
  const float sx = np_sumsq_f4(xr);

  // Resident half-row: 16 v2f = 32 VGPRs. (L1-hot reload of 8 float4.)
  v2f xv[16];
  {
    const float4* xh = xr + half * 8;
#pragma unroll
    for (int i = 0; i < 8; ++i) {
      float4 q = xh[i];
      xv[2 * i + 0] = (v2f){q.x, q.y};
      xv[2 * i + 1] = (v2f){q.z, q.w};
    }
  }
  __syncthreads();

  const float4* wbase = (const float4*)w;
  float best_d = 3.4e38f;
  int best_c = 0;

#pragma unroll 2
  for (int j = 0; j < CPC; ++j) {
    const int c = c0 + j;
    const float4* wr = wbase + ((size_t)c << 4) + (half << 3);
    v2f acc = (v2f){0.f, 0.f};
#pragma unroll
    for (int i = 0; i < 8; ++i) {
      float4 q = wr[i];                    // 2-line broadcast load (L1)
      acc += (v2f){q.x, q.y} * xv[2 * i + 0];   // v_pk_fma_f32
      acc += (v2f){q.z, q.w} * xv[2 * i + 1];
    }
    float s = acc.x + acc.y;
    float dot = s + __shfl_xor(s, 1, 64);  // halves combine (add commutes)
    float ad = sx + se[j];
    float d = fmaf(-2.0f, dot, ad);
    if (d < best_d) { best_d = d; best_c = c; }
  }

  unsigned long long key =
      ((unsigned long long)__float_as_uint(best_d) << 32) | (unsigned int)best_c;
  if (half == 0) keys4[((size_t)row << 2) | chunk] = key;
}

// Kernel B: 4-way key min -> index; indices (as float), STE quantized output
// x + fl(w - x), fp64 loss via shuffle reduce + one atomic per block; last
// block (device-scope counter) finalizes the commitment loss.
__global__ __launch_bounds__(256) void vq_out(const float* __restrict__ x,
                                              const float* __restrict__ w,
                                              const unsigned long long* __restrict__ keys4,
                                              float* __restrict__ outq,
                                              float* __restrict__ outidx,
                                              double* __restrict__ loss,
                                              unsigned int* __restrict__ cnt,
                                              float* __restrict__ outloss) {
  __shared__ int sidx[RPB];
  __shared__ double part[4];
  const int b = blockIdx.x, t = threadIdx.x;

  if (t < RPB) {
    const int row = b * RPB + t;
    const unsigned long long* kr = keys4 + ((size_t)row << 2);
    unsigned long long k0 = kr[0], k1 = kr[1], k2 = kr[2], k3 = kr[3];
    unsigned long long ka = k0 < k1 ? k0 : k1;
    unsigned long long kb = k2 < k3 ? k2 : k3;
    unsigned long long k = ka < kb ? ka : kb;
    const int idx = (int)(unsigned int)(k & 0xFFFFFFFFull);
    outidx[row] = (float)idx;
    sidx[t] = idx;
  }
  __syncthreads();

  double acc = 0.0;
  const float4* x4 = (const float4*)x;
  float4* o4 = (float4*)outq;
#pragma unroll
  for (int i = 0; i < 8; ++i) {
    const int e = i * 256 + t;
    const int rl = e >> 4;
    const int d4 = e & 15;
    const size_t gofs = ((size_t)b * RPB + rl) * 16 + d4;
    float4 xvv = x4[gofs];
    const float4* wr = (const float4*)(w + (size_t)sidx[rl] * DIM);
    float4 wv = wr[d4];
    float tx = wv.x - xvv.x, ty = wv.y - xvv.y;
    float tz = wv.z - xvv.z, tw = wv.w - xvv.w;
    float4 q;
    q.x = xvv.x + tx; q.y = xvv.y + ty;   // ref STE: x + fl(q - x)
    q.z = xvv.z + tz; q.w = xvv.w + tw;
    o4[gofs] = q;
    acc += (double)tx * tx + (double)ty * ty + (double)tz * tz + (double)tw * tw;
  }

#pragma unroll
  for (int s = 32; s > 0; s >>= 1) acc += __shfl_down(acc, s, 64);
  if ((t & 63) == 0) part[t >> 6] = acc;
  __syncthreads();
  if (t == 0) {
    atomicAdd(loss, (part[0] + part[1]) + (part[2] + part[3]));
    __threadfence();
    unsigned int old = atomicAdd(cnt, 1u);
    if (old == NBLK_B - 1) {
      double L = atomicAdd(loss, 0.0);   // all adds happened-before
      *outloss = 0.5f * (float)(L / (double)NELEM);
    }
  }
}

extern "C" void kernel_launch(void* const* d_in, const int* in_sizes, int n_in,
                              void* d_out, int out_size, void* d_ws, size_t ws_size,
                              hipStream_t stream) {
  const float* x = (const float*)d_in[0];   // inputs (32,64,32,32) fp32
  const float* w = (const float*)d_in[1];   // weight (1024,64) fp32

  float* outq    = (float*)d_out;           // [0, 2097152)
  float* outidx  = outq + NELEM;            // [2097152, +32768)
  float* outloss = outidx + NROWS;          // [2129920]

  char* wsb = (char*)d_ws;
  double* loss = (double*)wsb;                                   // 8 B
  unsigned int* cnt = (unsigned int*)(wsb + 64);                 // 4 B
  unsigned long long* keys4 = (unsigned long long*)(wsb + 256);  // 1 MB

  hipLaunchKernelGGL(vq_dist, dim3(1024),  dim3(256), 0, stream,
                     x, w, keys4, loss, cnt);
  hipLaunchKernelGGL(vq_out,  dim3(NBLK_B), dim3(256), 0, stream,
                     x, w, keys4, outq, outidx, loss, cnt, outloss);
}

// Round 4
// 152.856 us; speedup vs baseline: 3.4941x; 3.4941x over previous
//
#include <hip/hip_runtime.h>

#define NROWS  32768
#define DIM    64
#define KCODES 1024
#define NELEM  (NROWS * DIM)      // 2097152
#define CHUNKS 8
#define CPC    128                // codes per chunk
#define NBLK_B 512                // vq_out blocks
#define RPB_B  64                 // rows per vq_out block

typedef float v2f __attribute__((ext_vector_type(2)));

// numpy pairwise sum-of-squares over 16 float4 (64 elems): 8 accumulators,
// r[k] sums v[8i+k] over i, combine ((r0+r1)+(r2+r3))+((r4+r5)+(r6+r7)).
// contract(off): numpy squares into a temp then sums — no FMA fusion allowed.
// Verified bit-exact (absmax 0.0) in rounds 1-3.
__device__ __forceinline__ float np_sumsq_f4(const float4* __restrict__ p) {
#pragma clang fp contract(off)
  float4 a = p[0], b = p[1];
  float r0 = a.x * a.x, r1 = a.y * a.y, r2 = a.z * a.z, r3 = a.w * a.w;
  float r4 = b.x * b.x, r5 = b.y * b.y, r6 = b.z * b.z, r7 = b.w * b.w;
#pragma unroll
  for (int i = 1; i < 8; ++i) {
    a = p[2 * i]; b = p[2 * i + 1];
    r0 += a.x * a.x; r1 += a.y * a.y; r2 += a.z * a.z; r3 += a.w * a.w;
    r4 += b.x * b.x; r5 += b.y * b.y; r6 += b.z * b.z; r7 += b.w * b.w;
  }
  return ((r0 + r1) + (r2 + r3)) + ((r4 + r5) + (r6 + r7));
}

// Kernel A: fused se-prep + distances + per-chunk argmin.
// Grid 1024 = 128 row-groups x 8 K-chunks; 4 blocks/CU, 4 waves/SIMD
// (VGPR budget 128). One thread per row, FULL row resident in VGPRs —
// enforced with an empty inline-asm "+v" pin on each v2f so the allocator
// CANNOT rematerialize the loads (rounds 2-3: it silently demoted both the
// 64-float and 32-float arrays to in-loop global reloads -> VMEM-bound).
// w addresses are wave-uniform -> scalar s_load path (K$), off the VALU
// critical path. No cross-lane ops in the loop (round 3's shfl-per-code was
// a 7x latency-chain regression).
// d = fmaf(-2, dot, fl(sx+se[c])) — bit-exact vs ref's fl(fl(sx+se)-fl(2dot))
// since fl(2*dot) is exact. Ascending strict-< scan keeps lowest index on
// in-chunk ties; cross-chunk ties via u64 key min (index in low bits).
__global__ __launch_bounds__(256, 4) void vq_dist(const float* __restrict__ x,
                                                  const float* __restrict__ w,
                                                  unsigned long long* __restrict__ keys,
                                                  double* __restrict__ loss,
                                                  unsigned int* __restrict__ cnt) {
  __shared__ float se[CPC];
  const int t = threadIdx.x;
  const int g = blockIdx.x >> 3;
  const int chunk = blockIdx.x & 7;
  const int c0 = chunk * CPC;

  if (blockIdx.x == 0 && t == 0) { *loss = 0.0; *cnt = 0u; }

  // se for this chunk's 128 codes (numpy pairwise rounding).
  if (t < CPC)
    se[t] = np_sumsq_f4((const float4*)(w + (size_t)(c0 + t) * DIM));

  const int row = g * 256 + t;
  const float4* xr = (const float4*)(x + (size_t)row * DIM);
  const float sx = np_sumsq_f4(xr);

  // Resident row: 32 v2f = 64 VGPRs, pinned.
  v2f xv[32];
#pragma unroll
  for (int i = 0; i < 16; ++i) {
    float4 q = xr[i];
    xv[2 * i + 0] = (v2f){q.x, q.y};
    xv[2 * i + 1] = (v2f){q.z, q.w};
  }
#pragma unroll
  for (int i = 0; i < 32; ++i) asm volatile("" : "+v"(xv[i]));

  __syncthreads();

  const float4* wbase = (const float4*)w;
  float best_d = 3.4e38f;
  int best_c = c0;

#pragma unroll 2
  for (int j = 0; j < CPC; ++j) {
    const int c = c0 + j;
    const float4* wr = wbase + ((size_t)c << 4);   // uniform -> s_load / K$
    v2f a0 = (v2f){0.f, 0.f}, a1 = (v2f){0.f, 0.f};
    v2f a2 = (v2f){0.f, 0.f}, a3 = (v2f){0.f, 0.f};
#pragma unroll
    for (int i = 0; i < 16; i += 2) {
      float4 q0 = wr[i];
      float4 q1 = wr[i + 1];
      a0 += (v2f){q0.x, q0.y} * xv[2 * i + 0];   // v_pk_fma_f32
      a1 += (v2f){q0.z, q0.w} * xv[2 * i + 1];
      a2 += (v2f){q1.x, q1.y} * xv[2 * i + 2];
      a3 += (v2f){q1.z, q1.w} * xv[2 * i + 3];
    }
    v2f s = (a0 + a1) + (a2 + a3);
    float dot = s.x + s.y;
    float ad = sx + se[j];
    float d = fmaf(-2.0f, dot, ad);
    if (d < best_d) { best_d = d; best_c = c; }
  }

  keys[((size_t)row << 3) | chunk] =
      ((unsigned long long)__float_as_uint(best_d) << 32) | (unsigned int)best_c;
}

// Kernel B: 8-way key min -> index; indices (as float), STE quantized output
// x + fl(w - x) (bit-exact ref forward), fp64 loss shuffle-reduce + one
// atomic/block; last block (device counter) finalizes commitment loss.
__global__ __launch_bounds__(256) void vq_out(const float* __restrict__ x,
                                              const float* __restrict__ w,
                                              const unsigned long long* __restrict__ keys,
                                              float* __restrict__ outq,
                                              float* __restrict__ outidx,
                                              double* __restrict__ loss,
                                              unsigned int* __restrict__ cnt,
                                              float* __restrict__ outloss) {
  __shared__ int sidx[RPB_B];
  __shared__ double part[4];
  const int b = blockIdx.x, t = threadIdx.x;

  if (t < RPB_B) {
    const int row = b * RPB_B + t;
    const unsigned long long* kr = keys + ((size_t)row << 3);
    unsigned long long m = kr[0];
#pragma unroll
    for (int i = 1; i < 8; ++i) { unsigned long long k = kr[i]; if (k < m) m = k; }
    const int idx = (int)(unsigned int)(m & 0xFFFFFFFFull);
    outidx[row] = (float)idx;
    sidx[t] = idx;
  }
  __syncthreads();

  double acc = 0.0;
  const float4* x4 = (const float4*)x;
  float4* o4 = (float4*)outq;
#pragma unroll
  for (int i = 0; i < 4; ++i) {
    const int e = i * 256 + t;          // 0..1023 float4s of this block's rows
    const int rl = e >> 4;              // local row (0..63)
    const int d4 = e & 15;
    const size_t gofs = ((size_t)b * RPB_B + rl) * 16 + d4;
    float4 xvv = x4[gofs];
    const float4* wr = (const float4*)(w + (size_t)sidx[rl] * DIM);
    float4 wv = wr[d4];
    float tx = wv.x - xvv.x, ty = wv.y - xvv.y;
    float tz = wv.z - xvv.z, tw = wv.w - xvv.w;
    float4 q;
    q.x = xvv.x + tx; q.y = xvv.y + ty;   // ref STE: x + fl(q - x)
    q.z = xvv.z + tz; q.w = xvv.w + tw;
    o4[gofs] = q;
    acc += (double)tx * tx + (double)ty * ty + (double)tz * tz + (double)tw * tw;
  }

#pragma unroll
  for (int s = 32; s > 0; s >>= 1) acc += __shfl_down(acc, s, 64);
  if ((t & 63) == 0) part[t >> 6] = acc;
  __syncthreads();
  if (t == 0) {
    atomicAdd(loss, (part[0] + part[1]) + (part[2] + part[3]));
    __threadfence();
    unsigned int old = atomicAdd(cnt, 1u);
    if (old == NBLK_B - 1) {
      double L = atomicAdd(loss, 0.0);   // all adds happened-before
      *outloss = 0.5f * (float)(L / (double)NELEM);
    }
  }
}

extern "C" void kernel_launch(void* const* d_in, const int* in_sizes, int n_in,
                              void* d_out, int out_size, void* d_ws, size_t ws_size,
                              hipStream_t stream) {
  const float* x = (const float*)d_in[0];   // inputs (32,64,32,32) fp32
  const float* w = (const float*)d_in[1];   // weight (1024,64) fp32

  float* outq    = (float*)d_out;           // [0, 2097152)
  float* outidx  = outq + NELEM;            // [2097152, +32768)
  float* outloss = outidx + NROWS;          // [2129920]

  char* wsb = (char*)d_ws;
  double* loss = (double*)wsb;                                   // 8 B
  unsigned int* cnt = (unsigned int*)(wsb + 64);                 // 4 B
  unsigned long long* keys = (unsigned long long*)(wsb + 256);   // 2 MB

  hipLaunchKernelGGL(vq_dist, dim3(1024),  dim3(256), 0, stream,
                     x, w, keys, loss, cnt);
  hipLaunchKernelGGL(vq_out,  dim3(NBLK_B), dim3(256), 0, stream,
                     x, w, keys, outq, outidx, loss, cnt, outloss);
}